// Round 3
// baseline (416.915 us; speedup 1.0000x reference)
//
#include <hip/hip_runtime.h>
#include <hip/hip_bf16.h>
#include <stdint.h>

// VQ nearest-codebook: B=8,N=4096,C=256,K=8192
// R11 = R10 + A-fragments-in-registers. R10's counters showed LDS read BW on
// the critical path (64KB/CU/step, ~770cyc > 621cyc MFMA) and the A-frag reads
// are nt-invariant (same 32KB/wave re-read 32x). Fill aF[4][8] (128 VGPR) once
// from the swizzled LDS copy, then the steady-state step is 4 B ds_read_b128 +
// 16 MFMA only. Expected ~240 VGPR (2 waves/SIMD preserved).
// Pipeline (4-buf B ring, 2-step prefetch, counted vmcnt, 1 barrier/step,
// setprio around MFMA) and record/finalize unchanged - verified absmax=0 R10.

#define M_ROWS 32768   // B*N
#define KCODES 8192
#define CDIM   256
#define BM 128         // rows per block; A resident 128x256 fp16 = 64 KB
#define BNT 256        // codes per B tile
#define BK 32
#define NTILES 32      // KCODES / BNT
#define NREC 32        // records per row (each = top-2 over a 256-code subset)
#define MARGIN 0.75f   // >> hi-GEMM err (~0.32) + 2x key quantization (0.125)

typedef _Float16 f16x8 __attribute__((ext_vector_type(8)));
typedef _Float16 f16x4 __attribute__((ext_vector_type(4)));
typedef float    f32x4 __attribute__((ext_vector_type(4)));

#define WAITV(N) asm volatile("s_waitcnt vmcnt(" #N ")" ::: "memory")

__device__ __forceinline__ unsigned umin2(unsigned a, unsigned b) { return a < b ? a : b; }
__device__ __forceinline__ unsigned umax2(unsigned a, unsigned b) { return a > b ? a : b; }

// ---------------- prep: fp16 hi (scaled by 64) + row sq-norms ----------------
__global__ void vq_prep(const float* __restrict__ x, const float* __restrict__ cb,
                        _Float16* __restrict__ xhi, _Float16* __restrict__ cbhi,
                        float* __restrict__ xsq, float* __restrict__ cbsq) {
  const int wave = threadIdx.x >> 6, lane = threadIdx.x & 63;
  const int row = blockIdx.x * 4 + wave;     // one wave per row
  const float* src;
  _Float16* dhi;
  float* dsq;
  if (row < M_ROWS) {
    src = x + (size_t)row * CDIM;  dhi = xhi + (size_t)row * CDIM;  dsq = xsq + row;
  } else {
    const int r = row - M_ROWS;
    src = cb + (size_t)r * CDIM;   dhi = cbhi + (size_t)r * CDIM;   dsq = cbsq + r;
  }
  const float4 v = *(const float4*)(src + lane * 4);
  f16x4 h;
  h[0] = (_Float16)(v.x * 64.0f); h[1] = (_Float16)(v.y * 64.0f);
  h[2] = (_Float16)(v.z * 64.0f); h[3] = (_Float16)(v.w * 64.0f);
  *(f16x4*)(dhi + lane * 4) = h;
  float s = v.x * v.x + v.y * v.y + v.z * v.z + v.w * v.w;
  #pragma unroll
  for (int off = 32; off > 0; off >>= 1) s += __shfl_down(s, off, 64);
  if (lane == 0) *dsq = s;
}

// ---------------- pass1: A-resident hi GEMM + top-2 int-key records ----------------
__device__ __forceinline__ void gl16p(const void* g, void* l) {
  __builtin_amdgcn_global_load_lds(
      (const __attribute__((address_space(1))) unsigned int*)g,
      (__attribute__((address_space(3))) unsigned int*)l, 16, 0, 0);
}

__global__ __launch_bounds__(512, 2) void vq_pass1(
    const _Float16* __restrict__ xhi, const _Float16* __restrict__ cbhi,
    const float* __restrict__ cbsqg, uint2* __restrict__ srec) {
  extern __shared__ char smem[];
  _Float16* sA  = (_Float16*)smem;                    // 128 x 256 fp16 = 64 KB
  _Float16* sB  = (_Float16*)(smem + 65536);          // ring: 4 x (256x32 fp16 = 16 KB)
  float*    sCq = (float*)(smem + 65536 + 65536);     // 2 x 256 fp32 = 2 KB

  const int tid  = threadIdx.x;
  const int wave = tid >> 6, lane = tid & 63;
  const int quad = lane >> 4, l15 = lane & 15;
  const int mbase = blockIdx.x * BM;
  const int wrow = (wave >> 2) * 64;    // row half   (2 wave-groups)
  const int wcol = (wave & 3) * 64;     // col quarter (4 wave-slices)

  // ---- stage A once: row stride 512B = 32 x 16B slots; LDS(row,s)=Global(row,s^(row&7)).
  // Each gl16 covers 2 rows (64 lanes x 16B); 8 instrs per wave (8 waves).
  {
    const int ar = lane >> 5;            // row within pair
    const int as = lane & 31;            // 16B slot
    #pragma unroll
    for (int t = 0; t < 8; ++t) {
      const int rb  = (wave * 8 + t) * 2;
      const int row = rb + ar;
      const int slot = as ^ (row & 7);
      gl16p(xhi + (size_t)(mbase + row) * CDIM + slot * 8, sA + rb * CDIM);
    }
  }

  // B staging geometry (R2's measured-zero-conflict pattern): row stride 64B.
  const int srl  = lane >> 2;
  const int scol = (((lane & 3) ^ ((lane >> 3) & 3)) << 3);
  const int fcol = ((quad ^ ((l15 >> 1) & 3)) << 3);
  const int asw  = l15 & 7;             // A frag de-swizzle

  // stage the B tile for (nts,kss) into ring buffer bufidx: 2 gl16/wave
  auto stageB = [&](int nts, int kss, int bufidx) {
    const int cb0 = nts * BNT, kofs = kss * BK;
    _Float16* dst = sB + bufidx * (BNT * BK);
    #pragma unroll
    for (int t = 0; t < 2; ++t) {
      const int rb = wave * 32 + t * 16;
      gl16p(cbhi + (size_t)(cb0 + rb + srl) * CDIM + kofs + scol, dst + rb * BK);
    }
  };
  // cbsq tile for nt: all 8 waves redundantly write the same 1KB (benign)
  auto stageCq = [&](int nts) {
    gl16p(cbsqg + nts * BNT + lane * 4, sCq + (nts & 1) * BNT);
  };

  // prologue: prefetch steps 0 and 1 (A loads already in the queue, oldest)
  stageB(0, 0, 0); stageCq(0);
  stageB(0, 1, 1);

  // ---- one-time A-frag fill: drain own A loads (8 oldest; leave the 5 B/cq
  // loads in flight), barrier so ALL waves' A rows are visible, then read the
  // wave's full 64x256 A slice into registers (4 mf x 8 ks x f16x8 = 128 VGPR).
  WAITV(5);
  __builtin_amdgcn_s_barrier();
  asm volatile("" ::: "memory");
  f16x8 aF[4][8];
  #pragma unroll
  for (int mf = 0; mf < 4; ++mf) {
    const int arow = wrow + mf * 16 + l15;
    #pragma unroll
    for (int kk = 0; kk < 8; ++kk) {
      const int aslot = (kk * 4 + quad) ^ asw;       // 16B slot in resident A
      aF[mf][kk] = *(const f16x8*)(sA + arow * CDIM + aslot * 8);
    }
  }

  unsigned k1[4][4], k2[4][4];

  for (int nt = 0; nt < NTILES; ++nt) {
    const bool lastnt = (nt == NTILES - 1);
    if ((nt & 3) == 0) {   // open subchunk (4 nt x 64 cols = 256 codes / record)
      #pragma unroll
      for (int mf = 0; mf < 4; ++mf)
        #pragma unroll
        for (int i = 0; i < 4; ++i) { k1[mf][i] = 0x7fffffffu; k2[mf][i] = 0x7fffffffu; }
    }

    f32x4 acc[4][4];
    #pragma unroll
    for (int mf = 0; mf < 4; ++mf)
      #pragma unroll
      for (int nf = 0; nf < 4; ++nf) {
        f32x4 z = {0.0f, 0.0f, 0.0f, 0.0f};
        acc[mf][nf] = z;
      }

    #pragma unroll
    for (int ks = 0; ks < 8; ++ks) {
      // ---- stage step t+2 (t = nt*8+ks); ring index = (t+2)&3 = (ks+2)&3
      if (ks <= 5) {
        stageB(nt, ks + 2, (ks + 2) & 3);
      } else if (ks == 6) {
        if (!lastnt) { stageB(nt + 1, 0, 0); stageCq(nt + 1); }
      } else {  // ks == 7
        if (!lastnt) stageB(nt + 1, 1, 1);
      }
      // ---- counted wait: leave batches t+1,t+2 in flight (never vmcnt(0) mid-loop)
      // batch size = 2, +1 when the batch is an nt-opening step (carries cbsq)
      if (ks <= 5)      WAITV(4);
      else if (ks == 6) { if (!lastnt) WAITV(5); else WAITV(2); }
      else              { if (!lastnt) WAITV(5); else WAITV(0); }
      __builtin_amdgcn_s_barrier();
      asm volatile("" ::: "memory");

      // ---- compute step t from ring buffer ks&3 (A already in registers)
      const _Float16* sBc = sB + (ks & 3) * (BNT * BK);
      __builtin_amdgcn_s_setprio(1);
      #pragma unroll
      for (int nf = 0; nf < 4; ++nf) {
        const f16x8 bh = *(const f16x8*)(sBc + (wcol + nf * 16 + l15) * BK + fcol);
        #pragma unroll
        for (int mf = 0; mf < 4; ++mf)
          acc[mf][nf] = __builtin_amdgcn_mfma_f32_16x16x32_f16(aF[mf][ks], bh, acc[mf][nf], 0, 0, 0);
      }
      __builtin_amdgcn_s_setprio(0);
    }

    // int-key top-2 insert: key = (uint)(16*v + 32768) << 13 | col
    // v = cbsq - 2*dot; acc = 4096*dot => 16*v = (16*cbsq+32768) - acc/128
    #pragma unroll
    for (int nf = 0; nf < 4; ++nf) {
      const int cwl = wcol + nf * 16 + l15;         // col within nt tile
      const int col = nt * BNT + cwl;               // global code (C/D: col = lane&15)
      const float cq16 = fmaf(sCq[(nt & 1) * BNT + cwl], 16.0f, 32768.0f);
      #pragma unroll
      for (int mf = 0; mf < 4; ++mf)
        #pragma unroll
        for (int i = 0; i < 4; ++i) {
          const float kf = fmaf(acc[mf][nf][i], -0.0078125f, cq16);
          const unsigned key = ((unsigned)kf << 13) | (unsigned)col;
          k2[mf][i] = umin2(k2[mf][i], umax2(k1[mf][i], key));
          k1[mf][i] = umin2(k1[mf][i], key);
        }
    }

    if ((nt & 3) == 3) {   // close subchunk: 16-lane top-2 butterfly merge, store record
      const int g = (nt >> 2) * 4 + (wave & 3);     // 0..31
      #pragma unroll
      for (int mf = 0; mf < 4; ++mf)
        #pragma unroll
        for (int i = 0; i < 4; ++i) {
          unsigned a1 = k1[mf][i], a2 = k2[mf][i];
          #pragma unroll
          for (int m = 1; m <= 8; m <<= 1) {
            const unsigned o1 = (unsigned)__shfl_xor((int)a1, m, 64);
            const unsigned o2 = (unsigned)__shfl_xor((int)a2, m, 64);
            a2 = umin2(umin2(a2, o2), umax2(a1, o1));
            a1 = umin2(a1, o1);
          }
          if (l15 == 0) {
            const int rl = wrow + mf * 16 + quad * 4 + i;   // C/D row (0..127)
            uint2 r; r.x = a1; r.y = a2;
            srec[(size_t)(mbase + rl) * NREC + g] = r;
          }
        }
    }
  }
}

// ---------------- finalize: exact fp32 dots for margin candidates ----------------
__global__ void vq_finalize(const float* __restrict__ x, const float* __restrict__ cb,
                            const float* __restrict__ xsq, const float* __restrict__ cbsq,
                            const uint2* __restrict__ srec,
                            float* __restrict__ outIdx, float* __restrict__ outDist,
                            float* __restrict__ codes) {
  const int wave = threadIdx.x >> 6, lane = threadIdx.x & 63;
  const int row = blockIdx.x * 4 + wave;    // one wave per row
  uint2 rec;
  if (lane < NREC) rec = srec[(size_t)row * NREC + lane];
  else { rec.x = 0x7fffffffu; rec.y = 0x7fffffffu; }
  const float v1 = (float)(rec.x >> 13) * 0.0625f - 2048.0f;
  const float v2 = (float)(rec.y >> 13) * 0.0625f - 2048.0f;
  const int c1 = (int)(rec.x & 8191u);
  const int c2 = (int)(rec.y & 8191u);

  float gm = v1;
  #pragma unroll
  for (int m = 1; m <= 32; m <<= 1) gm = fminf(gm, __shfl_xor(gm, m, 64));
  const float thr = gm + MARGIN;
  unsigned long long mask1 = __ballot(v1 <= thr);
  unsigned long long mask2 = __ballot(v2 <= thr);

  const float4 xv = *(const float4*)(x + (size_t)row * CDIM + lane * 4);
  const float xq = xsq[row];
  float best = __builtin_inff(); int bidx = 1 << 30;

  #pragma unroll
  for (int pass = 0; pass < 2; ++pass) {
    unsigned long long m = pass ? mask2 : mask1;
    const int fi = pass ? c2 : c1;
    while (m) {
      const int g = __builtin_ctzll((long long)m); m &= m - 1;
      const int ci = __shfl(fi, g, 64);
      const float4 cv = *(const float4*)(cb + (size_t)ci * CDIM + lane * 4);
      float s = xv.x * cv.x + xv.y * cv.y + xv.z * cv.z + xv.w * cv.w;
      #pragma unroll
      for (int mm = 1; mm <= 32; mm <<= 1) s += __shfl_xor(s, mm, 64);
      const float dist = xq + cbsq[ci] - 2.0f * s;
      if (dist < best || (dist == best && ci < bidx)) { best = dist; bidx = ci; }
    }
  }

  if (lane == 0) { outIdx[row] = (float)bidx; outDist[row] = best; }
  const float4 cw = *(const float4*)(cb + (size_t)bidx * CDIM + lane * 4);
  *(float4*)(codes + (size_t)row * CDIM + lane * 4) = cw;
}

extern "C" void kernel_launch(void* const* d_in, const int* in_sizes, int n_in,
                              void* d_out, int out_size, void* d_ws, size_t ws_size,
                              hipStream_t stream) {
  const float* x  = (const float*)d_in[0];   // [8,4096,256] fp32
  const float* cb = (const float*)d_in[1];   // [8192,256] fp32
  float* out = (float*)d_out;                // codes | idx | dist

  char* w = (char*)d_ws;                     // ~29.2 MB
  _Float16* xhi  = (_Float16*)(w);                 // 16 MB
  _Float16* cbhi = (_Float16*)(w + 16777216);      //  4 MB
  float*    xsq  = (float*)   (w + 20971520);      // 128 KB
  float*    cbsq = (float*)   (w + 21102592);      //  32 KB
  uint2*    srec = (uint2*)   (w + 21135360);      //  8 MB (32768*32*8B)

  vq_prep<<<(M_ROWS + KCODES) / 4, 256, 0, stream>>>(x, cb, xhi, cbhi, xsq, cbsq);
  const size_t smem = 65536 + 65536 + 2048;  // A 64K + B ring 64K + cbsq 2K = 133120 B
  vq_pass1<<<dim3(M_ROWS / BM), 512, smem, stream>>>(xhi, cbhi, cbsq, srec);
  vq_finalize<<<M_ROWS / 4, 256, 0, stream>>>(x, cb, xsq, cbsq, srec,
                                              out + 8388608, out + 8421376, out);
}

// Round 4
// 415.914 us; speedup vs baseline: 1.0024x; 1.0024x over previous
//
#include <hip/hip_runtime.h>
#include <hip/hip_bf16.h>
#include <stdint.h>

// VQ nearest-codebook: B=8,N=4096,C=256,K=8192
// R12 = R11 with __launch_bounds__(512, 1). R11's regression was a VGPR-cap
// spill: hipcc treated launch_bounds' 2nd arg as 2 blocks/CU (CUDA-style) ->
// 4 waves/SIMD -> 128-VGPR cap -> aF[4][8] (128 VGPRs) spilled to scratch
// (FETCH 25->208 MB, WRITE 8->40 MB, pass1 203->344us). LDS=133KB already
// forces 1 block/CU, so (512,1) loses nothing and raises the cap to 256.
// A-fragments-in-registers theory unchanged: steady-state step = 4 B
// ds_read_b128 + 16 MFMA, no A LDS reads (they are nt-invariant, filled once).
// Pipeline (4-buf B ring, 2-step prefetch, counted vmcnt, 1 barrier/step,
// setprio) and record/finalize unchanged - verified absmax=0 R10/R11.

#define M_ROWS 32768   // B*N
#define KCODES 8192
#define CDIM   256
#define BM 128         // rows per block; A resident 128x256 fp16 = 64 KB
#define BNT 256        // codes per B tile
#define BK 32
#define NTILES 32      // KCODES / BNT
#define NREC 32        // records per row (each = top-2 over a 256-code subset)
#define MARGIN 0.75f   // >> hi-GEMM err (~0.32) + 2x key quantization (0.125)

typedef _Float16 f16x8 __attribute__((ext_vector_type(8)));
typedef _Float16 f16x4 __attribute__((ext_vector_type(4)));
typedef float    f32x4 __attribute__((ext_vector_type(4)));

#define WAITV(N) asm volatile("s_waitcnt vmcnt(" #N ")" ::: "memory")

__device__ __forceinline__ unsigned umin2(unsigned a, unsigned b) { return a < b ? a : b; }
__device__ __forceinline__ unsigned umax2(unsigned a, unsigned b) { return a > b ? a : b; }

// ---------------- prep: fp16 hi (scaled by 64) + row sq-norms ----------------
__global__ void vq_prep(const float* __restrict__ x, const float* __restrict__ cb,
                        _Float16* __restrict__ xhi, _Float16* __restrict__ cbhi,
                        float* __restrict__ xsq, float* __restrict__ cbsq) {
  const int wave = threadIdx.x >> 6, lane = threadIdx.x & 63;
  const int row = blockIdx.x * 4 + wave;     // one wave per row
  const float* src;
  _Float16* dhi;
  float* dsq;
  if (row < M_ROWS) {
    src = x + (size_t)row * CDIM;  dhi = xhi + (size_t)row * CDIM;  dsq = xsq + row;
  } else {
    const int r = row - M_ROWS;
    src = cb + (size_t)r * CDIM;   dhi = cbhi + (size_t)r * CDIM;   dsq = cbsq + r;
  }
  const float4 v = *(const float4*)(src + lane * 4);
  f16x4 h;
  h[0] = (_Float16)(v.x * 64.0f); h[1] = (_Float16)(v.y * 64.0f);
  h[2] = (_Float16)(v.z * 64.0f); h[3] = (_Float16)(v.w * 64.0f);
  *(f16x4*)(dhi + lane * 4) = h;
  float s = v.x * v.x + v.y * v.y + v.z * v.z + v.w * v.w;
  #pragma unroll
  for (int off = 32; off > 0; off >>= 1) s += __shfl_down(s, off, 64);
  if (lane == 0) *dsq = s;
}

// ---------------- pass1: A-resident hi GEMM + top-2 int-key records ----------------
__device__ __forceinline__ void gl16p(const void* g, void* l) {
  __builtin_amdgcn_global_load_lds(
      (const __attribute__((address_space(1))) unsigned int*)g,
      (__attribute__((address_space(3))) unsigned int*)l, 16, 0, 0);
}

__global__ __launch_bounds__(512, 1) void vq_pass1(
    const _Float16* __restrict__ xhi, const _Float16* __restrict__ cbhi,
    const float* __restrict__ cbsqg, uint2* __restrict__ srec) {
  extern __shared__ char smem[];
  _Float16* sA  = (_Float16*)smem;                    // 128 x 256 fp16 = 64 KB
  _Float16* sB  = (_Float16*)(smem + 65536);          // ring: 4 x (256x32 fp16 = 16 KB)
  float*    sCq = (float*)(smem + 65536 + 65536);     // 2 x 256 fp32 = 2 KB

  const int tid  = threadIdx.x;
  const int wave = tid >> 6, lane = tid & 63;
  const int quad = lane >> 4, l15 = lane & 15;
  const int mbase = blockIdx.x * BM;
  const int wrow = (wave >> 2) * 64;    // row half   (2 wave-groups)
  const int wcol = (wave & 3) * 64;     // col quarter (4 wave-slices)

  // ---- stage A once: row stride 512B = 32 x 16B slots; LDS(row,s)=Global(row,s^(row&7)).
  // Each gl16 covers 2 rows (64 lanes x 16B); 8 instrs per wave (8 waves).
  {
    const int ar = lane >> 5;            // row within pair
    const int as = lane & 31;            // 16B slot
    #pragma unroll
    for (int t = 0; t < 8; ++t) {
      const int rb  = (wave * 8 + t) * 2;
      const int row = rb + ar;
      const int slot = as ^ (row & 7);
      gl16p(xhi + (size_t)(mbase + row) * CDIM + slot * 8, sA + rb * CDIM);
    }
  }

  // B staging geometry (R2's measured-zero-conflict pattern): row stride 64B.
  const int srl  = lane >> 2;
  const int scol = (((lane & 3) ^ ((lane >> 3) & 3)) << 3);
  const int fcol = ((quad ^ ((l15 >> 1) & 3)) << 3);
  const int asw  = l15 & 7;             // A frag de-swizzle

  // stage the B tile for (nts,kss) into ring buffer bufidx: 2 gl16/wave
  auto stageB = [&](int nts, int kss, int bufidx) {
    const int cb0 = nts * BNT, kofs = kss * BK;
    _Float16* dst = sB + bufidx * (BNT * BK);
    #pragma unroll
    for (int t = 0; t < 2; ++t) {
      const int rb = wave * 32 + t * 16;
      gl16p(cbhi + (size_t)(cb0 + rb + srl) * CDIM + kofs + scol, dst + rb * BK);
    }
  };
  // cbsq tile for nt: all 8 waves redundantly write the same 1KB (benign)
  auto stageCq = [&](int nts) {
    gl16p(cbsqg + nts * BNT + lane * 4, sCq + (nts & 1) * BNT);
  };

  // prologue: prefetch steps 0 and 1 (A loads already in the queue, oldest)
  stageB(0, 0, 0); stageCq(0);
  stageB(0, 1, 1);

  // ---- one-time A-frag fill: drain own A loads (8 oldest; leave the 5 B/cq
  // loads in flight), barrier so ALL waves' A rows are visible, then read the
  // wave's full 64x256 A slice into registers (4 mf x 8 ks x f16x8 = 128 VGPR).
  WAITV(5);
  __builtin_amdgcn_s_barrier();
  asm volatile("" ::: "memory");
  f16x8 aF[4][8];
  #pragma unroll
  for (int mf = 0; mf < 4; ++mf) {
    const int arow = wrow + mf * 16 + l15;
    #pragma unroll
    for (int kk = 0; kk < 8; ++kk) {
      const int aslot = (kk * 4 + quad) ^ asw;       // 16B slot in resident A
      aF[mf][kk] = *(const f16x8*)(sA + arow * CDIM + aslot * 8);
    }
  }

  unsigned k1[4][4], k2[4][4];

  for (int nt = 0; nt < NTILES; ++nt) {
    const bool lastnt = (nt == NTILES - 1);
    if ((nt & 3) == 0) {   // open subchunk (4 nt x 64 cols = 256 codes / record)
      #pragma unroll
      for (int mf = 0; mf < 4; ++mf)
        #pragma unroll
        for (int i = 0; i < 4; ++i) { k1[mf][i] = 0x7fffffffu; k2[mf][i] = 0x7fffffffu; }
    }

    f32x4 acc[4][4];
    #pragma unroll
    for (int mf = 0; mf < 4; ++mf)
      #pragma unroll
      for (int nf = 0; nf < 4; ++nf) {
        f32x4 z = {0.0f, 0.0f, 0.0f, 0.0f};
        acc[mf][nf] = z;
      }

    #pragma unroll
    for (int ks = 0; ks < 8; ++ks) {
      // ---- stage step t+2 (t = nt*8+ks); ring index = (t+2)&3 = (ks+2)&3
      if (ks <= 5) {
        stageB(nt, ks + 2, (ks + 2) & 3);
      } else if (ks == 6) {
        if (!lastnt) { stageB(nt + 1, 0, 0); stageCq(nt + 1); }
      } else {  // ks == 7
        if (!lastnt) stageB(nt + 1, 1, 1);
      }
      // ---- counted wait: leave batches t+1,t+2 in flight (never vmcnt(0) mid-loop)
      // batch size = 2, +1 when the batch is an nt-opening step (carries cbsq)
      if (ks <= 5)      WAITV(4);
      else if (ks == 6) { if (!lastnt) WAITV(5); else WAITV(2); }
      else              { if (!lastnt) WAITV(5); else WAITV(0); }
      __builtin_amdgcn_s_barrier();
      asm volatile("" ::: "memory");

      // ---- compute step t from ring buffer ks&3 (A already in registers)
      const _Float16* sBc = sB + (ks & 3) * (BNT * BK);
      __builtin_amdgcn_s_setprio(1);
      #pragma unroll
      for (int nf = 0; nf < 4; ++nf) {
        const f16x8 bh = *(const f16x8*)(sBc + (wcol + nf * 16 + l15) * BK + fcol);
        #pragma unroll
        for (int mf = 0; mf < 4; ++mf)
          acc[mf][nf] = __builtin_amdgcn_mfma_f32_16x16x32_f16(aF[mf][ks], bh, acc[mf][nf], 0, 0, 0);
      }
      __builtin_amdgcn_s_setprio(0);
    }

    // int-key top-2 insert: key = (uint)(16*v + 32768) << 13 | col
    // v = cbsq - 2*dot; acc = 4096*dot => 16*v = (16*cbsq+32768) - acc/128
    #pragma unroll
    for (int nf = 0; nf < 4; ++nf) {
      const int cwl = wcol + nf * 16 + l15;         // col within nt tile
      const int col = nt * BNT + cwl;               // global code (C/D: col = lane&15)
      const float cq16 = fmaf(sCq[(nt & 1) * BNT + cwl], 16.0f, 32768.0f);
      #pragma unroll
      for (int mf = 0; mf < 4; ++mf)
        #pragma unroll
        for (int i = 0; i < 4; ++i) {
          const float kf = fmaf(acc[mf][nf][i], -0.0078125f, cq16);
          const unsigned key = ((unsigned)kf << 13) | (unsigned)col;
          k2[mf][i] = umin2(k2[mf][i], umax2(k1[mf][i], key));
          k1[mf][i] = umin2(k1[mf][i], key);
        }
    }

    if ((nt & 3) == 3) {   // close subchunk: 16-lane top-2 butterfly merge, store record
      const int g = (nt >> 2) * 4 + (wave & 3);     // 0..31
      #pragma unroll
      for (int mf = 0; mf < 4; ++mf)
        #pragma unroll
        for (int i = 0; i < 4; ++i) {
          unsigned a1 = k1[mf][i], a2 = k2[mf][i];
          #pragma unroll
          for (int m = 1; m <= 8; m <<= 1) {
            const unsigned o1 = (unsigned)__shfl_xor((int)a1, m, 64);
            const unsigned o2 = (unsigned)__shfl_xor((int)a2, m, 64);
            a2 = umin2(umin2(a2, o2), umax2(a1, o1));
            a1 = umin2(a1, o1);
          }
          if (l15 == 0) {
            const int rl = wrow + mf * 16 + quad * 4 + i;   // C/D row (0..127)
            uint2 r; r.x = a1; r.y = a2;
            srec[(size_t)(mbase + rl) * NREC + g] = r;
          }
        }
    }
  }
}

// ---------------- finalize: exact fp32 dots for margin candidates ----------------
__global__ void vq_finalize(const float* __restrict__ x, const float* __restrict__ cb,
                            const float* __restrict__ xsq, const float* __restrict__ cbsq,
                            const uint2* __restrict__ srec,
                            float* __restrict__ outIdx, float* __restrict__ outDist,
                            float* __restrict__ codes) {
  const int wave = threadIdx.x >> 6, lane = threadIdx.x & 63;
  const int row = blockIdx.x * 4 + wave;    // one wave per row
  uint2 rec;
  if (lane < NREC) rec = srec[(size_t)row * NREC + lane];
  else { rec.x = 0x7fffffffu; rec.y = 0x7fffffffu; }
  const float v1 = (float)(rec.x >> 13) * 0.0625f - 2048.0f;
  const float v2 = (float)(rec.y >> 13) * 0.0625f - 2048.0f;
  const int c1 = (int)(rec.x & 8191u);
  const int c2 = (int)(rec.y & 8191u);

  float gm = v1;
  #pragma unroll
  for (int m = 1; m <= 32; m <<= 1) gm = fminf(gm, __shfl_xor(gm, m, 64));
  const float thr = gm + MARGIN;
  unsigned long long mask1 = __ballot(v1 <= thr);
  unsigned long long mask2 = __ballot(v2 <= thr);

  const float4 xv = *(const float4*)(x + (size_t)row * CDIM + lane * 4);
  const float xq = xsq[row];
  float best = __builtin_inff(); int bidx = 1 << 30;

  #pragma unroll
  for (int pass = 0; pass < 2; ++pass) {
    unsigned long long m = pass ? mask2 : mask1;
    const int fi = pass ? c2 : c1;
    while (m) {
      const int g = __builtin_ctzll((long long)m); m &= m - 1;
      const int ci = __shfl(fi, g, 64);
      const float4 cv = *(const float4*)(cb + (size_t)ci * CDIM + lane * 4);
      float s = xv.x * cv.x + xv.y * cv.y + xv.z * cv.z + xv.w * cv.w;
      #pragma unroll
      for (int mm = 1; mm <= 32; mm <<= 1) s += __shfl_xor(s, mm, 64);
      const float dist = xq + cbsq[ci] - 2.0f * s;
      if (dist < best || (dist == best && ci < bidx)) { best = dist; bidx = ci; }
    }
  }

  if (lane == 0) { outIdx[row] = (float)bidx; outDist[row] = best; }
  const float4 cw = *(const float4*)(cb + (size_t)bidx * CDIM + lane * 4);
  *(float4*)(codes + (size_t)row * CDIM + lane * 4) = cw;
}

extern "C" void kernel_launch(void* const* d_in, const int* in_sizes, int n_in,
                              void* d_out, int out_size, void* d_ws, size_t ws_size,
                              hipStream_t stream) {
  const float* x  = (const float*)d_in[0];   // [8,4096,256] fp32
  const float* cb = (const float*)d_in[1];   // [8192,256] fp32
  float* out = (float*)d_out;                // codes | idx | dist

  char* w = (char*)d_ws;                     // ~29.2 MB
  _Float16* xhi  = (_Float16*)(w);                 // 16 MB
  _Float16* cbhi = (_Float16*)(w + 16777216);      //  4 MB
  float*    xsq  = (float*)   (w + 20971520);      // 128 KB
  float*    cbsq = (float*)   (w + 21102592);      //  32 KB
  uint2*    srec = (uint2*)   (w + 21135360);      //  8 MB (32768*32*8B)

  vq_prep<<<(M_ROWS + KCODES) / 4, 256, 0, stream>>>(x, cb, xhi, cbhi, xsq, cbsq);
  const size_t smem = 65536 + 65536 + 2048;  // A 64K + B ring 64K + cbsq 2K = 133120 B
  vq_pass1<<<dim3(M_ROWS / BM), 512, smem, stream>>>(xhi, cbhi, cbsq, srec);
  vq_finalize<<<M_ROWS / 4, 256, 0, stream>>>(x, cb, xsq, cbsq, srec,
                                              out + 8388608, out + 8421376, out);
}

// Round 5
// 288.905 us; speedup vs baseline: 1.4431x; 1.4396x over previous
//
#include <hip/hip_runtime.h>
#include <hip/hip_bf16.h>
#include <stdint.h>

// VQ nearest-codebook: B=8,N=4096,C=256,K=8192
// R13 = half-A-in-registers + explicit waves_per_eu. R11/R12 showed the
// allocator pins this kernel at 128 VGPRs (both launch_bounds variants) and
// spilled the full aF[4][8] (128 regs) to scratch (FETCH 25->212 MB).
// Fix: (a) aF[2][8] only (64 regs; mf=0,1), mf=2,3 read from LDS per step
// (R10's proven path) -> peak demand ~205 regs; (b) amdgpu_waves_per_eu(2)
// attribute to set the 256-reg budget explicitly, launch_bounds carries only
// the block size. Per-step LDS: 6 reads (2A+4B) = 48KB/CU ~= 565cyc, at/below
// the 621cyc MFMA floor (R10 had 8 reads = 770cyc, above it).
// Pipeline (4-buf B ring, 2-step prefetch, counted vmcnt, 1 barrier/step,
// setprio) and record/finalize unchanged - verified absmax=0 R10/R11/R12.

#define M_ROWS 32768   // B*N
#define KCODES 8192
#define CDIM   256
#define BM 128         // rows per block; A resident 128x256 fp16 = 64 KB
#define BNT 256        // codes per B tile
#define BK 32
#define NTILES 32      // KCODES / BNT
#define NREC 32        // records per row (each = top-2 over a 256-code subset)
#define MARGIN 0.75f   // >> hi-GEMM err (~0.32) + 2x key quantization (0.125)

typedef _Float16 f16x8 __attribute__((ext_vector_type(8)));
typedef _Float16 f16x4 __attribute__((ext_vector_type(4)));
typedef float    f32x4 __attribute__((ext_vector_type(4)));

#define WAITV(N) asm volatile("s_waitcnt vmcnt(" #N ")" ::: "memory")

__device__ __forceinline__ unsigned umin2(unsigned a, unsigned b) { return a < b ? a : b; }
__device__ __forceinline__ unsigned umax2(unsigned a, unsigned b) { return a > b ? a : b; }

// ---------------- prep: fp16 hi (scaled by 64) + row sq-norms ----------------
__global__ void vq_prep(const float* __restrict__ x, const float* __restrict__ cb,
                        _Float16* __restrict__ xhi, _Float16* __restrict__ cbhi,
                        float* __restrict__ xsq, float* __restrict__ cbsq) {
  const int wave = threadIdx.x >> 6, lane = threadIdx.x & 63;
  const int row = blockIdx.x * 4 + wave;     // one wave per row
  const float* src;
  _Float16* dhi;
  float* dsq;
  if (row < M_ROWS) {
    src = x + (size_t)row * CDIM;  dhi = xhi + (size_t)row * CDIM;  dsq = xsq + row;
  } else {
    const int r = row - M_ROWS;
    src = cb + (size_t)r * CDIM;   dhi = cbhi + (size_t)r * CDIM;   dsq = cbsq + r;
  }
  const float4 v = *(const float4*)(src + lane * 4);
  f16x4 h;
  h[0] = (_Float16)(v.x * 64.0f); h[1] = (_Float16)(v.y * 64.0f);
  h[2] = (_Float16)(v.z * 64.0f); h[3] = (_Float16)(v.w * 64.0f);
  *(f16x4*)(dhi + lane * 4) = h;
  float s = v.x * v.x + v.y * v.y + v.z * v.z + v.w * v.w;
  #pragma unroll
  for (int off = 32; off > 0; off >>= 1) s += __shfl_down(s, off, 64);
  if (lane == 0) *dsq = s;
}

// ---------------- pass1: A-resident hi GEMM + top-2 int-key records ----------------
__device__ __forceinline__ void gl16p(const void* g, void* l) {
  __builtin_amdgcn_global_load_lds(
      (const __attribute__((address_space(1))) unsigned int*)g,
      (__attribute__((address_space(3))) unsigned int*)l, 16, 0, 0);
}

__global__ __attribute__((amdgpu_waves_per_eu(2))) __launch_bounds__(512) void vq_pass1(
    const _Float16* __restrict__ xhi, const _Float16* __restrict__ cbhi,
    const float* __restrict__ cbsqg, uint2* __restrict__ srec) {
  extern __shared__ char smem[];
  _Float16* sA  = (_Float16*)smem;                    // 128 x 256 fp16 = 64 KB
  _Float16* sB  = (_Float16*)(smem + 65536);          // ring: 4 x (256x32 fp16 = 16 KB)
  float*    sCq = (float*)(smem + 65536 + 65536);     // 2 x 256 fp32 = 2 KB

  const int tid  = threadIdx.x;
  const int wave = tid >> 6, lane = tid & 63;
  const int quad = lane >> 4, l15 = lane & 15;
  const int mbase = blockIdx.x * BM;
  const int wrow = (wave >> 2) * 64;    // row half   (2 wave-groups)
  const int wcol = (wave & 3) * 64;     // col quarter (4 wave-slices)

  // ---- stage A once: row stride 512B = 32 x 16B slots; LDS(row,s)=Global(row,s^(row&7)).
  // Each gl16 covers 2 rows (64 lanes x 16B); 8 instrs per wave (8 waves).
  {
    const int ar = lane >> 5;            // row within pair
    const int as = lane & 31;            // 16B slot
    #pragma unroll
    for (int t = 0; t < 8; ++t) {
      const int rb  = (wave * 8 + t) * 2;
      const int row = rb + ar;
      const int slot = as ^ (row & 7);
      gl16p(xhi + (size_t)(mbase + row) * CDIM + slot * 8, sA + rb * CDIM);
    }
  }

  // B staging geometry (R2's measured-zero-conflict pattern): row stride 64B.
  const int srl  = lane >> 2;
  const int scol = (((lane & 3) ^ ((lane >> 3) & 3)) << 3);
  const int fcol = ((quad ^ ((l15 >> 1) & 3)) << 3);
  const int asw  = l15 & 7;             // A frag de-swizzle

  // stage the B tile for (nts,kss) into ring buffer bufidx: 2 gl16/wave
  auto stageB = [&](int nts, int kss, int bufidx) {
    const int cb0 = nts * BNT, kofs = kss * BK;
    _Float16* dst = sB + bufidx * (BNT * BK);
    #pragma unroll
    for (int t = 0; t < 2; ++t) {
      const int rb = wave * 32 + t * 16;
      gl16p(cbhi + (size_t)(cb0 + rb + srl) * CDIM + kofs + scol, dst + rb * BK);
    }
  };
  // cbsq tile for nt: all 8 waves redundantly write the same 1KB (benign)
  auto stageCq = [&](int nts) {
    gl16p(cbsqg + nts * BNT + lane * 4, sCq + (nts & 1) * BNT);
  };

  // prologue: prefetch steps 0 and 1 (A loads already in the queue, oldest)
  stageB(0, 0, 0); stageCq(0);
  stageB(0, 1, 1);

  // ---- one-time half-A fill: drain own A loads (8 oldest; leave the 5 B/cq
  // loads in flight), barrier so ALL waves' A rows are visible, then read
  // mf=0,1 of the wave's A slice into registers (2 mf x 8 ks x f16x8 = 64 VGPR).
  WAITV(5);
  __builtin_amdgcn_s_barrier();
  asm volatile("" ::: "memory");
  f16x8 aF[2][8];
  #pragma unroll
  for (int mf = 0; mf < 2; ++mf) {
    const int arow = wrow + mf * 16 + l15;
    #pragma unroll
    for (int kk = 0; kk < 8; ++kk) {
      const int aslot = (kk * 4 + quad) ^ asw;       // 16B slot in resident A
      aF[mf][kk] = *(const f16x8*)(sA + arow * CDIM + aslot * 8);
    }
  }

  unsigned k1[4][4], k2[4][4];

  for (int nt = 0; nt < NTILES; ++nt) {
    const bool lastnt = (nt == NTILES - 1);
    if ((nt & 3) == 0) {   // open subchunk (4 nt x 64 cols = 256 codes / record)
      #pragma unroll
      for (int mf = 0; mf < 4; ++mf)
        #pragma unroll
        for (int i = 0; i < 4; ++i) { k1[mf][i] = 0x7fffffffu; k2[mf][i] = 0x7fffffffu; }
    }

    f32x4 acc[4][4];
    #pragma unroll
    for (int mf = 0; mf < 4; ++mf)
      #pragma unroll
      for (int nf = 0; nf < 4; ++nf) {
        f32x4 z = {0.0f, 0.0f, 0.0f, 0.0f};
        acc[mf][nf] = z;
      }

    #pragma unroll
    for (int ks = 0; ks < 8; ++ks) {
      // ---- stage step t+2 (t = nt*8+ks); ring index = (t+2)&3 = (ks+2)&3
      if (ks <= 5) {
        stageB(nt, ks + 2, (ks + 2) & 3);
      } else if (ks == 6) {
        if (!lastnt) { stageB(nt + 1, 0, 0); stageCq(nt + 1); }
      } else {  // ks == 7
        if (!lastnt) stageB(nt + 1, 1, 1);
      }
      // ---- counted wait: leave batches t+1,t+2 in flight (never vmcnt(0) mid-loop)
      // batch size = 2, +1 when the batch is an nt-opening step (carries cbsq)
      if (ks <= 5)      WAITV(4);
      else if (ks == 6) { if (!lastnt) WAITV(5); else WAITV(2); }
      else              { if (!lastnt) WAITV(5); else WAITV(0); }
      __builtin_amdgcn_s_barrier();
      asm volatile("" ::: "memory");

      // ---- compute step t from ring buffer ks&3 (mf=0,1 A in regs; mf=2,3 from LDS)
      const _Float16* sBc = sB + (ks & 3) * (BNT * BK);
      const int aslot = (ks * 4 + quad) ^ asw;       // 16B slot in resident A
      f16x8 ah2[2];
      #pragma unroll
      for (int mh = 0; mh < 2; ++mh) {
        const int arow = wrow + (2 + mh) * 16 + l15;
        ah2[mh] = *(const f16x8*)(sA + arow * CDIM + aslot * 8);
      }
      __builtin_amdgcn_s_setprio(1);
      #pragma unroll
      for (int nf = 0; nf < 4; ++nf) {
        const f16x8 bh = *(const f16x8*)(sBc + (wcol + nf * 16 + l15) * BK + fcol);
        acc[0][nf] = __builtin_amdgcn_mfma_f32_16x16x32_f16(aF[0][ks], bh, acc[0][nf], 0, 0, 0);
        acc[1][nf] = __builtin_amdgcn_mfma_f32_16x16x32_f16(aF[1][ks], bh, acc[1][nf], 0, 0, 0);
        acc[2][nf] = __builtin_amdgcn_mfma_f32_16x16x32_f16(ah2[0],    bh, acc[2][nf], 0, 0, 0);
        acc[3][nf] = __builtin_amdgcn_mfma_f32_16x16x32_f16(ah2[1],    bh, acc[3][nf], 0, 0, 0);
      }
      __builtin_amdgcn_s_setprio(0);
    }

    // int-key top-2 insert: key = (uint)(16*v + 32768) << 13 | col
    // v = cbsq - 2*dot; acc = 4096*dot => 16*v = (16*cbsq+32768) - acc/128
    #pragma unroll
    for (int nf = 0; nf < 4; ++nf) {
      const int cwl = wcol + nf * 16 + l15;         // col within nt tile
      const int col = nt * BNT + cwl;               // global code (C/D: col = lane&15)
      const float cq16 = fmaf(sCq[(nt & 1) * BNT + cwl], 16.0f, 32768.0f);
      #pragma unroll
      for (int mf = 0; mf < 4; ++mf)
        #pragma unroll
        for (int i = 0; i < 4; ++i) {
          const float kf = fmaf(acc[mf][nf][i], -0.0078125f, cq16);
          const unsigned key = ((unsigned)kf << 13) | (unsigned)col;
          k2[mf][i] = umin2(k2[mf][i], umax2(k1[mf][i], key));
          k1[mf][i] = umin2(k1[mf][i], key);
        }
    }

    if ((nt & 3) == 3) {   // close subchunk: 16-lane top-2 butterfly merge, store record
      const int g = (nt >> 2) * 4 + (wave & 3);     // 0..31
      #pragma unroll
      for (int mf = 0; mf < 4; ++mf)
        #pragma unroll
        for (int i = 0; i < 4; ++i) {
          unsigned a1 = k1[mf][i], a2 = k2[mf][i];
          #pragma unroll
          for (int m = 1; m <= 8; m <<= 1) {
            const unsigned o1 = (unsigned)__shfl_xor((int)a1, m, 64);
            const unsigned o2 = (unsigned)__shfl_xor((int)a2, m, 64);
            a2 = umin2(umin2(a2, o2), umax2(a1, o1));
            a1 = umin2(a1, o1);
          }
          if (l15 == 0) {
            const int rl = wrow + mf * 16 + quad * 4 + i;   // C/D row (0..127)
            uint2 r; r.x = a1; r.y = a2;
            srec[(size_t)(mbase + rl) * NREC + g] = r;
          }
        }
    }
  }
}

// ---------------- finalize: exact fp32 dots for margin candidates ----------------
__global__ void vq_finalize(const float* __restrict__ x, const float* __restrict__ cb,
                            const float* __restrict__ xsq, const float* __restrict__ cbsq,
                            const uint2* __restrict__ srec,
                            float* __restrict__ outIdx, float* __restrict__ outDist,
                            float* __restrict__ codes) {
  const int wave = threadIdx.x >> 6, lane = threadIdx.x & 63;
  const int row = blockIdx.x * 4 + wave;    // one wave per row
  uint2 rec;
  if (lane < NREC) rec = srec[(size_t)row * NREC + lane];
  else { rec.x = 0x7fffffffu; rec.y = 0x7fffffffu; }
  const float v1 = (float)(rec.x >> 13) * 0.0625f - 2048.0f;
  const float v2 = (float)(rec.y >> 13) * 0.0625f - 2048.0f;
  const int c1 = (int)(rec.x & 8191u);
  const int c2 = (int)(rec.y & 8191u);

  float gm = v1;
  #pragma unroll
  for (int m = 1; m <= 32; m <<= 1) gm = fminf(gm, __shfl_xor(gm, m, 64));
  const float thr = gm + MARGIN;
  unsigned long long mask1 = __ballot(v1 <= thr);
  unsigned long long mask2 = __ballot(v2 <= thr);

  const float4 xv = *(const float4*)(x + (size_t)row * CDIM + lane * 4);
  const float xq = xsq[row];
  float best = __builtin_inff(); int bidx = 1 << 30;

  #pragma unroll
  for (int pass = 0; pass < 2; ++pass) {
    unsigned long long m = pass ? mask2 : mask1;
    const int fi = pass ? c2 : c1;
    while (m) {
      const int g = __builtin_ctzll((long long)m); m &= m - 1;
      const int ci = __shfl(fi, g, 64);
      const float4 cv = *(const float4*)(cb + (size_t)ci * CDIM + lane * 4);
      float s = xv.x * cv.x + xv.y * cv.y + xv.z * cv.z + xv.w * cv.w;
      #pragma unroll
      for (int mm = 1; mm <= 32; mm <<= 1) s += __shfl_xor(s, mm, 64);
      const float dist = xq + cbsq[ci] - 2.0f * s;
      if (dist < best || (dist == best && ci < bidx)) { best = dist; bidx = ci; }
    }
  }

  if (lane == 0) { outIdx[row] = (float)bidx; outDist[row] = best; }
  const float4 cw = *(const float4*)(cb + (size_t)bidx * CDIM + lane * 4);
  *(float4*)(codes + (size_t)row * CDIM + lane * 4) = cw;
}

extern "C" void kernel_launch(void* const* d_in, const int* in_sizes, int n_in,
                              void* d_out, int out_size, void* d_ws, size_t ws_size,
                              hipStream_t stream) {
  const float* x  = (const float*)d_in[0];   // [8,4096,256] fp32
  const float* cb = (const float*)d_in[1];   // [8192,256] fp32
  float* out = (float*)d_out;                // codes | idx | dist

  char* w = (char*)d_ws;                     // ~29.2 MB
  _Float16* xhi  = (_Float16*)(w);                 // 16 MB
  _Float16* cbhi = (_Float16*)(w + 16777216);      //  4 MB
  float*    xsq  = (float*)   (w + 20971520);      // 128 KB
  float*    cbsq = (float*)   (w + 21102592);      //  32 KB
  uint2*    srec = (uint2*)   (w + 21135360);      //  8 MB (32768*32*8B)

  vq_prep<<<(M_ROWS + KCODES) / 4, 256, 0, stream>>>(x, cb, xhi, cbhi, xsq, cbsq);
  const size_t smem = 65536 + 65536 + 2048;  // A 64K + B ring 64K + cbsq 2K = 133120 B
  vq_pass1<<<dim3(M_ROWS / BM), 512, smem, stream>>>(xhi, cbhi, cbsq, srec);
  vq_finalize<<<M_ROWS / 4, 256, 0, stream>>>(x, cb, xsq, cbsq, srec,
                                              out + 8388608, out + 8421376, out);
}

// Round 6
// 279.422 us; speedup vs baseline: 1.4921x; 1.0339x over previous
//
#include <hip/hip_runtime.h>
#include <hip/hip_bf16.h>
#include <stdint.h>

// VQ nearest-codebook: B=8,N=4096,C=256,K=8192
// R14 = barrier-free pass1. R8/R10/R13 all plateau ~200-230us at MfmaUtil
// 26-29% with per-step all-wave barriers (convoy: ds_read burst / MFMA burst
// serialize at 2 waves/SIMD). Fix: per-wave PRIVATE B streams - wave w owns
// rows (w>>2)*64 and col-quarter (w&3) of each 256-tile, stages its own 4KB
// B slice (ring-2, global_load_lds, per-wave vmcnt, WAITV(0) once/iter with
// a full compute phase of latency budget). ZERO barriers after the one-time
// A fill; waves skew freely, SIMD co-schedules MFMA vs memory phases.
// Cost: B fetched 2x from L2 (codebook fp16 = 4MB = one XCD L2, absorbed).
// cbsq: 4 scalar reg loads per nt (LDS cq dropped). Output mapping (cols,
// records, keys) IDENTICAL to verified R10/R13 - absmax must stay 0.

#define M_ROWS 32768   // B*N
#define KCODES 8192
#define CDIM   256
#define BM 128         // rows per block; A resident 128x256 fp16 = 64 KB
#define BNT 256        // codes per tile
#define BK 32
#define NTILES 32      // KCODES / BNT
#define NREC 32        // records per row (each = top-2 over a 256-code subset)
#define MARGIN 0.75f   // >> hi-GEMM err (~0.32) + 2x key quantization (0.125)

typedef _Float16 f16x8 __attribute__((ext_vector_type(8)));
typedef _Float16 f16x4 __attribute__((ext_vector_type(4)));
typedef float    f32x4 __attribute__((ext_vector_type(4)));

#define WAITV(N) asm volatile("s_waitcnt vmcnt(" #N ")" ::: "memory")

__device__ __forceinline__ unsigned umin2(unsigned a, unsigned b) { return a < b ? a : b; }
__device__ __forceinline__ unsigned umax2(unsigned a, unsigned b) { return a > b ? a : b; }

// ---------------- prep: fp16 hi (scaled by 64) + row sq-norms ----------------
__global__ void vq_prep(const float* __restrict__ x, const float* __restrict__ cb,
                        _Float16* __restrict__ xhi, _Float16* __restrict__ cbhi,
                        float* __restrict__ xsq, float* __restrict__ cbsq) {
  const int wave = threadIdx.x >> 6, lane = threadIdx.x & 63;
  const int row = blockIdx.x * 4 + wave;     // one wave per row
  const float* src;
  _Float16* dhi;
  float* dsq;
  if (row < M_ROWS) {
    src = x + (size_t)row * CDIM;  dhi = xhi + (size_t)row * CDIM;  dsq = xsq + row;
  } else {
    const int r = row - M_ROWS;
    src = cb + (size_t)r * CDIM;   dhi = cbhi + (size_t)r * CDIM;   dsq = cbsq + r;
  }
  const float4 v = *(const float4*)(src + lane * 4);
  f16x4 h;
  h[0] = (_Float16)(v.x * 64.0f); h[1] = (_Float16)(v.y * 64.0f);
  h[2] = (_Float16)(v.z * 64.0f); h[3] = (_Float16)(v.w * 64.0f);
  *(f16x4*)(dhi + lane * 4) = h;
  float s = v.x * v.x + v.y * v.y + v.z * v.z + v.w * v.w;
  #pragma unroll
  for (int off = 32; off > 0; off >>= 1) s += __shfl_down(s, off, 64);
  if (lane == 0) *dsq = s;
}

// ---------------- pass1: A-resident hi GEMM + top-2 int-key records ----------------
__device__ __forceinline__ void gl16p(const void* g, void* l) {
  __builtin_amdgcn_global_load_lds(
      (const __attribute__((address_space(1))) unsigned int*)g,
      (__attribute__((address_space(3))) unsigned int*)l, 16, 0, 0);
}

__global__ __launch_bounds__(512) void vq_pass1(
    const _Float16* __restrict__ xhi, const _Float16* __restrict__ cbhi,
    const float* __restrict__ cbsqg, uint2* __restrict__ srec) {
  extern __shared__ char smem[];
  _Float16* sA = (_Float16*)smem;                 // 128 x 256 fp16 = 64 KB (shared, RO)
  _Float16* sB = (_Float16*)(smem + 65536);       // 8 waves x 2 bufs x 2048 elems = 64 KB

  const int tid  = threadIdx.x;
  const int wave = tid >> 6, lane = tid & 63;
  const int quad = lane >> 4, l15 = lane & 15;
  const int mbase = blockIdx.x * BM;
  const int wrow = (wave >> 2) * 64;    // row half
  const int q    = wave & 3;            // col quarter
  const int wcol = q * 64;

  // ---- stage A once: row stride 512B = 32 x 16B slots; LDS(row,s)=Global(row,s^(row&7)).
  {
    const int ar = lane >> 5;            // row within pair
    const int as = lane & 31;            // 16B slot
    #pragma unroll
    for (int t = 0; t < 8; ++t) {
      const int rb  = (wave * 8 + t) * 2;
      const int row = rb + ar;
      const int slot = as ^ (row & 7);
      gl16p(xhi + (size_t)(mbase + row) * CDIM + slot * 8, sA + rb * CDIM);
    }
  }

  // B staging geometry (R2's measured-zero-conflict pattern): row stride 64B.
  const int srl  = lane >> 2;
  const int scol = (((lane & 3) ^ ((lane >> 3) & 3)) << 3);
  const int fcol = ((quad ^ ((l15 >> 1) & 3)) << 3);
  const int asw  = l15 & 7;             // A frag de-swizzle

  _Float16* sBw = sB + wave * 4096;     // this wave's private 8 KB (2 x 2048 elems)

  // stage this wave's 64x32 B slice for (nts,kss) into private buffer buf
  auto stageB = [&](int nts, int kss, int buf) {
    const int c0 = nts * BNT + wcol;
    const int kofs = kss * BK;
    _Float16* dst = sBw + buf * 2048;
    #pragma unroll
    for (int t = 0; t < 4; ++t)
      gl16p(cbhi + (size_t)(c0 + t * 16 + srl) * CDIM + kofs + scol, dst + t * 512);
  };

  // cbsq for current/next tile in registers (4 scalar loads per nt)
  float cq_cur[4], cq_nxt[4];
  #pragma unroll
  for (int j = 0; j < 4; ++j) cq_cur[j] = cbsqg[wcol + j * 16 + l15];

  // prologue: stage iter-0 buffer, drain A (leave the 4 B loads in flight),
  // one barrier so all waves' A rows are visible. Last barrier in the kernel.
  stageB(0, 0, 0);
  WAITV(4);
  __builtin_amdgcn_s_barrier();
  asm volatile("" ::: "memory");

  unsigned k1[4][4], k2[4][4];

  for (int nt = 0; nt < NTILES; ++nt) {
    const bool lastnt = (nt == NTILES - 1);
    if ((nt & 3) == 0) {   // open subchunk (4 nt x 64 cols = 256 codes / record)
      #pragma unroll
      for (int mf = 0; mf < 4; ++mf)
        #pragma unroll
        for (int i = 0; i < 4; ++i) { k1[mf][i] = 0x7fffffffu; k2[mf][i] = 0x7fffffffu; }
    }

    f32x4 acc[4][4];
    #pragma unroll
    for (int mf = 0; mf < 4; ++mf)
      #pragma unroll
      for (int nf = 0; nf < 4; ++nf) {
        f32x4 z = {0.0f, 0.0f, 0.0f, 0.0f};
        acc[mf][nf] = z;
      }

    #pragma unroll
    for (int ks = 0; ks < 8; ++ks) {
      // ---- own buffer for step t=nt*8+ks ready (its loads were issued one
      // full compute phase ago). Per-wave wait; no barrier.
      WAITV(0);
      asm volatile("" ::: "memory");
      // ---- stage step t+1 into the other private buffer (last read at t-1,
      // whose ds_reads completed before t-1's MFMAs; safe to overwrite).
      if (ks < 7)        stageB(nt, ks + 1, (ks + 1) & 1);
      else if (!lastnt)  stageB(nt + 1, 0, 0);
      if (ks == 6 && !lastnt) {
        #pragma unroll
        for (int j = 0; j < 4; ++j)
          cq_nxt[j] = cbsqg[(nt + 1) * BNT + wcol + j * 16 + l15];
      }

      // ---- compute step t from private buffer ks&1
      const _Float16* sBc = sBw + (ks & 1) * 2048;
      const int aslot = (ks * 4 + quad) ^ asw;       // 16B slot in resident A
      f16x8 ah[4];
      #pragma unroll
      for (int mf = 0; mf < 4; ++mf)
        ah[mf] = *(const f16x8*)(sA + (wrow + mf * 16 + l15) * CDIM + aslot * 8);
      __builtin_amdgcn_s_setprio(1);
      #pragma unroll
      for (int nf = 0; nf < 4; ++nf) {
        const f16x8 bh = *(const f16x8*)(sBc + (nf * 16 + l15) * BK + fcol);
        #pragma unroll
        for (int mf = 0; mf < 4; ++mf)
          acc[mf][nf] = __builtin_amdgcn_mfma_f32_16x16x32_f16(ah[mf], bh, acc[mf][nf], 0, 0, 0);
      }
      __builtin_amdgcn_s_setprio(0);
    }

    // int-key top-2 insert: key = (uint)(16*v + 32768) << 13 | col
    // v = cbsq - 2*dot; acc = 4096*dot => 16*v = (16*cbsq+32768) - acc/128
    #pragma unroll
    for (int nf = 0; nf < 4; ++nf) {
      const int col = nt * BNT + wcol + nf * 16 + l15;   // global code (C/D: col = lane&15)
      const float cq16 = fmaf(cq_cur[nf], 16.0f, 32768.0f);
      #pragma unroll
      for (int mf = 0; mf < 4; ++mf)
        #pragma unroll
        for (int i = 0; i < 4; ++i) {
          const float kf = fmaf(acc[mf][nf][i], -0.0078125f, cq16);
          const unsigned key = ((unsigned)kf << 13) | (unsigned)col;
          k2[mf][i] = umin2(k2[mf][i], umax2(k1[mf][i], key));
          k1[mf][i] = umin2(k1[mf][i], key);
        }
    }

    if ((nt & 3) == 3) {   // close subchunk: 16-lane top-2 butterfly merge, store record
      const int g = (nt >> 2) * 4 + q;              // 0..31
      #pragma unroll
      for (int mf = 0; mf < 4; ++mf)
        #pragma unroll
        for (int i = 0; i < 4; ++i) {
          unsigned a1 = k1[mf][i], a2 = k2[mf][i];
          #pragma unroll
          for (int m = 1; m <= 8; m <<= 1) {
            const unsigned o1 = (unsigned)__shfl_xor((int)a1, m, 64);
            const unsigned o2 = (unsigned)__shfl_xor((int)a2, m, 64);
            a2 = umin2(umin2(a2, o2), umax2(a1, o1));
            a1 = umin2(a1, o1);
          }
          if (l15 == 0) {
            const int rl = wrow + mf * 16 + quad * 4 + i;   // C/D row (0..127)
            uint2 r; r.x = a1; r.y = a2;
            srec[(size_t)(mbase + rl) * NREC + g] = r;
          }
        }
    }

    #pragma unroll
    for (int j = 0; j < 4; ++j) cq_cur[j] = cq_nxt[j];
  }
}

// ---------------- finalize: exact fp32 dots for margin candidates ----------------
__global__ void vq_finalize(const float* __restrict__ x, const float* __restrict__ cb,
                            const float* __restrict__ xsq, const float* __restrict__ cbsq,
                            const uint2* __restrict__ srec,
                            float* __restrict__ outIdx, float* __restrict__ outDist,
                            float* __restrict__ codes) {
  const int wave = threadIdx.x >> 6, lane = threadIdx.x & 63;
  const int row = blockIdx.x * 4 + wave;    // one wave per row
  uint2 rec;
  if (lane < NREC) rec = srec[(size_t)row * NREC + lane];
  else { rec.x = 0x7fffffffu; rec.y = 0x7fffffffu; }
  const float v1 = (float)(rec.x >> 13) * 0.0625f - 2048.0f;
  const float v2 = (float)(rec.y >> 13) * 0.0625f - 2048.0f;
  const int c1 = (int)(rec.x & 8191u);
  const int c2 = (int)(rec.y & 8191u);

  float gm = v1;
  #pragma unroll
  for (int m = 1; m <= 32; m <<= 1) gm = fminf(gm, __shfl_xor(gm, m, 64));
  const float thr = gm + MARGIN;
  unsigned long long mask1 = __ballot(v1 <= thr);
  unsigned long long mask2 = __ballot(v2 <= thr);

  const float4 xv = *(const float4*)(x + (size_t)row * CDIM + lane * 4);
  const float xq = xsq[row];
  float best = __builtin_inff(); int bidx = 1 << 30;

  #pragma unroll
  for (int pass = 0; pass < 2; ++pass) {
    unsigned long long m = pass ? mask2 : mask1;
    const int fi = pass ? c2 : c1;
    while (m) {
      const int g = __builtin_ctzll((long long)m); m &= m - 1;
      const int ci = __shfl(fi, g, 64);
      const float4 cv = *(const float4*)(cb + (size_t)ci * CDIM + lane * 4);
      float s = xv.x * cv.x + xv.y * cv.y + xv.z * cv.z + xv.w * cv.w;
      #pragma unroll
      for (int mm = 1; mm <= 32; mm <<= 1) s += __shfl_xor(s, mm, 64);
      const float dist = xq + cbsq[ci] - 2.0f * s;
      if (dist < best || (dist == best && ci < bidx)) { best = dist; bidx = ci; }
    }
  }

  if (lane == 0) { outIdx[row] = (float)bidx; outDist[row] = best; }
  const float4 cw = *(const float4*)(cb + (size_t)bidx * CDIM + lane * 4);
  *(float4*)(codes + (size_t)row * CDIM + lane * 4) = cw;
}

extern "C" void kernel_launch(void* const* d_in, const int* in_sizes, int n_in,
                              void* d_out, int out_size, void* d_ws, size_t ws_size,
                              hipStream_t stream) {
  const float* x  = (const float*)d_in[0];   // [8,4096,256] fp32
  const float* cb = (const float*)d_in[1];   // [8192,256] fp32
  float* out = (float*)d_out;                // codes | idx | dist

  char* w = (char*)d_ws;                     // ~29.2 MB
  _Float16* xhi  = (_Float16*)(w);                 // 16 MB
  _Float16* cbhi = (_Float16*)(w + 16777216);      //  4 MB
  float*    xsq  = (float*)   (w + 20971520);      // 128 KB
  float*    cbsq = (float*)   (w + 21102592);      //  32 KB
  uint2*    srec = (uint2*)   (w + 21135360);      //  8 MB (32768*32*8B)

  vq_prep<<<(M_ROWS + KCODES) / 4, 256, 0, stream>>>(x, cb, xhi, cbhi, xsq, cbsq);
  const size_t smem = 65536 + 65536;  // A 64K + private B 64K = 131072 B
  vq_pass1<<<dim3(M_ROWS / BM), 512, smem, stream>>>(xhi, cbhi, cbsq, srec);
  vq_finalize<<<M_ROWS / 4, 256, 0, stream>>>(x, cb, xsq, cbsq, srec,
                                              out + 8388608, out + 8421376, out);
}